// Round 6
// baseline (566.565 us; speedup 1.0000x reference)
//
#include <hip/hip_runtime.h>

#define HEADS 4

// ---------------- GEMM: C[M,Ncols] = A[M,K] @ B[K,Ncols] ----------------
__global__ __launch_bounds__(256)
void gemm_k(const float* __restrict__ A, const float* __restrict__ B,
            float* __restrict__ C, int M, int K, int Ncols) {
    constexpr int BM = 128, BN = 32, BK = 32;
    __shared__ float As[BK][BM];
    __shared__ float Bs[BK][BN];
    const int m0 = blockIdx.x * BM;
    const int n0 = blockIdx.y * BN;
    const int tid = threadIdx.x;
    const int ty = tid >> 3;
    const int tx = tid & 7;
    float acc[4][4] = {};
    for (int kt = 0; kt < K; kt += BK) {
        #pragma unroll
        for (int it = 0; it < 4; ++it) {
            int i = tid + 256 * it;
            int row = i >> 3;
            int kc = (i & 7) * 4;
            int grow = m0 + row;
            float4 v = make_float4(0.f, 0.f, 0.f, 0.f);
            if (grow < M)
                v = *(const float4*)&A[(size_t)grow * K + kt + kc];
            As[kc + 0][row] = v.x;
            As[kc + 1][row] = v.y;
            As[kc + 2][row] = v.z;
            As[kc + 3][row] = v.w;
        }
        {
            int kr = tid >> 3;
            int nc = (tid & 7) * 4;
            *(float4*)&Bs[kr][nc] =
                *(const float4*)&B[(size_t)(kt + kr) * Ncols + n0 + nc];
        }
        __syncthreads();
        #pragma unroll
        for (int k = 0; k < BK; ++k) {
            float4 av = *(const float4*)&As[k][ty * 4];
            float4 bv = *(const float4*)&Bs[k][tx * 4];
            float a[4] = {av.x, av.y, av.z, av.w};
            float b[4] = {bv.x, bv.y, bv.z, bv.w};
            #pragma unroll
            for (int i = 0; i < 4; ++i)
                #pragma unroll
                for (int j = 0; j < 4; ++j)
                    acc[i][j] += a[i] * b[j];
        }
        __syncthreads();
    }
    #pragma unroll
    for (int i = 0; i < 4; ++i) {
        int grow = m0 + ty * 4 + i;
        if (grow < M) {
            float4 v = make_float4(acc[i][0], acc[i][1], acc[i][2], acc[i][3]);
            *(float4*)&C[(size_t)grow * Ncols + n0 + tx * 4] = v;
        }
    }
}

// ---------------- per-node alpha + sigmoid ----------------
__global__ __launch_bounds__(256)
void alpha_k(const float* __restrict__ xh, const float* __restrict__ attq,
             float* __restrict__ sa, int n, int C, int HC) {
    const int t = blockIdx.x * blockDim.x + threadIdx.x;
    if (t >= n * HEADS) return;
    const int nd = t >> 2, h = t & 3;
    const float* xr = &xh[(size_t)nd * HC + h * C];
    const float* q = &attq[h * C];
    float s = 0.f;
    for (int c = 0; c < C; c += 4) {
        float4 a = *(const float4*)&xr[c];
        float4 b = *(const float4*)&q[c];
        s += a.x * b.x + a.y * b.y + a.z * b.z + a.w * b.w;
    }
    sa[t] = 1.0f / (1.0f + __expf(-s));
}

// ---------------- CSR build (dst-sorted), once per launch ----------------
__global__ __launch_bounds__(256)
void hist_k(const int* __restrict__ dst, int* __restrict__ deg, int E) {
    int e = blockIdx.x * 256 + threadIdx.x;
    if (e < E) atomicAdd(&deg[dst[e]], 1);
}

__global__ __launch_bounds__(256)
void scan1_k(const int* __restrict__ deg, int* __restrict__ ro,
             int* __restrict__ bsum, int n) {
    __shared__ int s[256];
    int i = blockIdx.x * 256 + threadIdx.x;
    int v = (i < n) ? deg[i] : 0;
    s[threadIdx.x] = v;
    __syncthreads();
    for (int off = 1; off < 256; off <<= 1) {
        int t = (threadIdx.x >= off) ? s[threadIdx.x - off] : 0;
        __syncthreads();
        s[threadIdx.x] += t;
        __syncthreads();
    }
    if (i < n) ro[i] = s[threadIdx.x] - v;
    if (threadIdx.x == 255) bsum[blockIdx.x] = s[255];
}

__global__ __launch_bounds__(256)
void scan2_k(int* __restrict__ bsum, int nb) {
    __shared__ int s[256];
    int v = (threadIdx.x < nb) ? bsum[threadIdx.x] : 0;
    s[threadIdx.x] = v;
    __syncthreads();
    for (int off = 1; off < 256; off <<= 1) {
        int t = (threadIdx.x >= off) ? s[threadIdx.x - off] : 0;
        __syncthreads();
        s[threadIdx.x] += t;
        __syncthreads();
    }
    if (threadIdx.x < nb) bsum[threadIdx.x] = s[threadIdx.x] - v;
}

__global__ __launch_bounds__(256)
void scan3_k(int* __restrict__ ro, int* __restrict__ cur,
             const int* __restrict__ bsum, int n, int E) {
    int i = blockIdx.x * 256 + threadIdx.x;
    if (i < n) {
        int r = ro[i] + bsum[i >> 8];
        ro[i] = r;
        cur[i] = r;
    }
    if (i == 0) ro[n] = E;
}

__global__ __launch_bounds__(256)
void scatter_idx_k(const int* __restrict__ src, const int* __restrict__ dst,
                   int* __restrict__ cur, int* __restrict__ csr_src, int E) {
    int e = blockIdx.x * 256 + threadIdx.x;
    if (e >= E) return;
    int d = dst[e];
    int pos = atomicAdd(&cur[d], 1);
    csr_src[pos] = src[e];
}

// ---------------- fused logit+softmax+aggregate+epilogue ----------------
// One wave per node. lane = 4*e_loc + h (16 edges x 4 heads per pass).
// SINGLE row read: the lane that computes w_e[h] holds the head-h quarter of
// xs in registers and FMAs it directly into acc[]. Final per-head sums are
// reduced across the 16 edge-lanes sharing h via shfl_xor, then routed
// through a tiny LDS buffer for a coalesced store.
template <int C, bool CONCAT>
__global__ __launch_bounds__(256)
void fused_edge_k(const int* __restrict__ ro, const int* __restrict__ csr_src,
                  const float* __restrict__ xh, const float* __restrict__ sa,
                  const float* __restrict__ attv, const float* __restrict__ bias,
                  float* __restrict__ outp, int n) {
    constexpr int HC = 4 * C;
    constexpr int QH = C / 4;  // float4 chunks per head quarter
    const int wid = threadIdx.x >> 6;
    const int lane = threadIdx.x & 63;
    const int node = blockIdx.x * 4 + wid;

    __shared__ float avs[HC];
    __shared__ float4 obuf[4][C];
    for (int i = threadIdx.x; i < HC; i += 256) avs[i] = attv[i];
    __syncthreads();
    if (node >= n) return;

    const float4* __restrict__ xh4 = (const float4*)xh;
    const float4* __restrict__ avs4 = (const float4*)avs;
    const int s0 = ro[node], s1 = ro[node + 1];

    const int e_loc = lane >> 2;
    const int h_l = lane & 3;
    const float sad = sa[node * 4 + h_l];

    // hoist: dst row quarter + attv quarter for this head
    float4 xd[QH], av[QH];
    #pragma unroll
    for (int i = 0; i < QH; ++i) {
        xd[i] = xh4[(size_t)node * C + h_l * QH + i];
        av[i] = avs4[h_l * QH + i];
    }

    float4 acc[QH];
    #pragma unroll
    for (int i = 0; i < QH; ++i) acc[i] = make_float4(0.f, 0.f, 0.f, 0.f);
    float ssum = 0.f;

    for (int base = s0; base < s1; base += 16) {
        const int j = base + e_loc;
        const bool valid = (j < s1);
        const int si = valid ? csr_src[j] : node;  // safe index for invalid lanes
        const float sas = sa[si * 4 + h_l];
        const float wa = 1.0f - fabsf(sad - sas);
        // load src row quarter (kept live for the FMA below)
        float4 xs[QH];
        #pragma unroll
        for (int i = 0; i < QH; ++i) xs[i] = xh4[(size_t)si * C + h_l * QH + i];
        float wb = 0.f;
        #pragma unroll
        for (int i = 0; i < QH; ++i) {
            const float4 a = xs[i];
            const float4 b = xd[i];
            const float4 v = av[i];
            float t0 = a.x + b.x; t0 = t0 > 0.f ? t0 : 0.01f * t0;
            float t1 = a.y + b.y; t1 = t1 > 0.f ? t1 : 0.01f * t1;
            float t2 = a.z + b.z; t2 = t2 > 0.f ? t2 : 0.01f * t2;
            float t3 = a.w + b.w; t3 = t3 > 0.f ? t3 : 0.01f * t3;
            wb += v.x * t0 + v.y * t1 + v.z * t2 + v.w * t3;
        }
        float w = valid ? __expf(fminf(wa * wb, 60.f)) : 0.f;
        ssum += w;
        #pragma unroll
        for (int i = 0; i < QH; ++i) {
            acc[i].x += w * xs[i].x;
            acc[i].y += w * xs[i].y;
            acc[i].z += w * xs[i].z;
            acc[i].w += w * xs[i].w;
        }
    }

    // reduce across the 16 edge-lanes sharing this head (bits 2..5 of lane)
    #pragma unroll
    for (int off = 4; off < 64; off <<= 1) {
        ssum += __shfl_xor(ssum, off, 64);
        #pragma unroll
        for (int i = 0; i < QH; ++i) {
            acc[i].x += __shfl_xor(acc[i].x, off, 64);
            acc[i].y += __shfl_xor(acc[i].y, off, 64);
            acc[i].z += __shfl_xor(acc[i].z, off, 64);
            acc[i].w += __shfl_xor(acc[i].w, off, 64);
        }
    }
    const float inv = 1.0f / (ssum + 1e-20f);

    // route to LDS for coalesced store: lane (e_loc,h) with e_loc<QH writes
    // float4 #e_loc of head h.
    if (e_loc < QH) {
        float4 myv = acc[0];
        #pragma unroll
        for (int i = 1; i < QH; ++i) if (e_loc == i) myv = acc[i];
        myv.x *= inv; myv.y *= inv; myv.z *= inv; myv.w *= inv;
        obuf[wid][h_l * QH + e_loc] = myv;
    }
    // same-wave LDS write->read (no barrier needed)
    if (CONCAT) {
        if (lane < C) {
            const float4 a = obuf[wid][lane];
            const float4 b = ((const float4*)bias)[lane];
            float4 v = make_float4(a.x + b.x, a.y + b.y, a.z + b.z, a.w + b.w);
            v.x = v.x > 0.f ? v.x : __expf(v.x) - 1.0f;
            v.y = v.y > 0.f ? v.y : __expf(v.y) - 1.0f;
            v.z = v.z > 0.f ? v.z : __expf(v.z) - 1.0f;
            v.w = v.w > 0.f ? v.w : __expf(v.w) - 1.0f;
            *(float4*)&outp[(size_t)node * HC + lane * 4] = v;
        }
    } else {
        if (lane < QH) {
            const float4 a0 = obuf[wid][lane];
            const float4 a1 = obuf[wid][lane + QH];
            const float4 a2 = obuf[wid][lane + 2 * QH];
            const float4 a3 = obuf[wid][lane + 3 * QH];
            const float4 b = ((const float4*)bias)[lane];
            float4 v;
            v.x = 0.25f * (a0.x + a1.x + a2.x + a3.x) + b.x;
            v.y = 0.25f * (a0.y + a1.y + a2.y + a3.y) + b.y;
            v.z = 0.25f * (a0.z + a1.z + a2.z + a3.z) + b.z;
            v.w = 0.25f * (a0.w + a1.w + a2.w + a3.w) + b.w;
            *(float4*)&outp[(size_t)node * C + lane * 4] = v;
        }
    }
}

extern "C" void kernel_launch(void* const* d_in, const int* in_sizes, int n_in,
                              void* d_out, int out_size, void* d_ws, size_t ws_size,
                              hipStream_t stream) {
    const float* x      = (const float*)d_in[0];
    const int*   src    = (const int*)d_in[1];
    const int*   dst    = (const int*)d_in[2];
    const float* lin1   = (const float*)d_in[3];
    const float* att_q1 = (const float*)d_in[4];
    const float* att_v1 = (const float*)d_in[5];
    const float* bias1  = (const float*)d_in[6];
    const float* lin2   = (const float*)d_in[7];
    const float* att_q2 = (const float*)d_in[8];
    const float* att_v2 = (const float*)d_in[9];
    const float* bias2  = (const float*)d_in[10];
    float* outp = (float*)d_out;

    const int n = in_sizes[0] / 256;
    const int E = in_sizes[1];
    const int nh = n * HEADS;
    const int NB = (n + 255) / 256;

    char* wsb = (char*)d_ws;
    size_t o = 0;
    float* xh     = (float*)(wsb + o); o += (size_t)n * 160 * 4;
    float* accb   = (float*)(wsb + o); o += (size_t)n * 160 * 4;
    float* sa     = (float*)(wsb + o); o += (size_t)nh * 4;
    int* csr_src  = (int*)(wsb + o); o += (size_t)E * 4;
    int* deg      = (int*)(wsb + o); o += (size_t)n * 4;
    int* ro       = (int*)(wsb + o); o += (size_t)(n + 1) * 4;
    int* cur      = (int*)(wsb + o); o += (size_t)n * 4;
    int* bsum     = (int*)(wsb + o); o += 256 * 4;

    dim3 blk(256);
    const int EG = (E + 255) / 256;

    // ---- CSR build (dst is layer-invariant: build once, use twice) ----
    hipMemsetAsync(deg, 0, (size_t)n * 4, stream);
    hist_k<<<EG, blk, 0, stream>>>(dst, deg, E);
    scan1_k<<<NB, blk, 0, stream>>>(deg, ro, bsum, n);
    scan2_k<<<1, blk, 0, stream>>>(bsum, NB);
    scan3_k<<<NB, blk, 0, stream>>>(ro, cur, bsum, n, E);
    scatter_idx_k<<<EG, blk, 0, stream>>>(src, dst, cur, csr_src, E);

    // ================= layer 1: C=32, HC=128, K=256 =================
    gemm_k<<<dim3((n + 127) / 128, 128 / 32), blk, 0, stream>>>(x, lin1, xh, n, 256, 128);
    alpha_k<<<(nh + 255) / 256, blk, 0, stream>>>(xh, att_q1, sa, n, 32, 128);
    fused_edge_k<32, true><<<(n + 3) / 4, blk, 0, stream>>>(ro, csr_src, xh, sa, att_v1, bias1, accb, n);

    // ================= layer 2: C=40, HC=160, K=128 =================
    gemm_k<<<dim3((n + 127) / 128, 160 / 32), blk, 0, stream>>>(accb, lin2, xh, n, 128, 160);
    alpha_k<<<(nh + 255) / 256, blk, 0, stream>>>(xh, att_q2, sa, n, 40, 160);
    fused_edge_k<40, false><<<(n + 3) / 4, blk, 0, stream>>>(ro, csr_src, xh, sa, att_v2, bias2, outp, n);
}

// Round 7
// 552.124 us; speedup vs baseline: 1.0262x; 1.0262x over previous
//
#include <hip/hip_runtime.h>

#define HEADS 4

// ---------------- GEMM: C[M,Ncols] = A[M,K] @ B[K,Ncols] ----------------
__global__ __launch_bounds__(256)
void gemm_k(const float* __restrict__ A, const float* __restrict__ B,
            float* __restrict__ C, int M, int K, int Ncols) {
    constexpr int BM = 128, BN = 32, BK = 32;
    __shared__ float As[BK][BM];
    __shared__ float Bs[BK][BN];
    const int m0 = blockIdx.x * BM;
    const int n0 = blockIdx.y * BN;
    const int tid = threadIdx.x;
    const int ty = tid >> 3;
    const int tx = tid & 7;
    float acc[4][4] = {};
    for (int kt = 0; kt < K; kt += BK) {
        #pragma unroll
        for (int it = 0; it < 4; ++it) {
            int i = tid + 256 * it;
            int row = i >> 3;
            int kc = (i & 7) * 4;
            int grow = m0 + row;
            float4 v = make_float4(0.f, 0.f, 0.f, 0.f);
            if (grow < M)
                v = *(const float4*)&A[(size_t)grow * K + kt + kc];
            As[kc + 0][row] = v.x;
            As[kc + 1][row] = v.y;
            As[kc + 2][row] = v.z;
            As[kc + 3][row] = v.w;
        }
        {
            int kr = tid >> 3;
            int nc = (tid & 7) * 4;
            *(float4*)&Bs[kr][nc] =
                *(const float4*)&B[(size_t)(kt + kr) * Ncols + n0 + nc];
        }
        __syncthreads();
        #pragma unroll
        for (int k = 0; k < BK; ++k) {
            float4 av = *(const float4*)&As[k][ty * 4];
            float4 bv = *(const float4*)&Bs[k][tx * 4];
            float a[4] = {av.x, av.y, av.z, av.w};
            float b[4] = {bv.x, bv.y, bv.z, bv.w};
            #pragma unroll
            for (int i = 0; i < 4; ++i)
                #pragma unroll
                for (int j = 0; j < 4; ++j)
                    acc[i][j] += a[i] * b[j];
        }
        __syncthreads();
    }
    #pragma unroll
    for (int i = 0; i < 4; ++i) {
        int grow = m0 + ty * 4 + i;
        if (grow < M) {
            float4 v = make_float4(acc[i][0], acc[i][1], acc[i][2], acc[i][3]);
            *(float4*)&C[(size_t)grow * Ncols + n0 + tx * 4] = v;
        }
    }
}

// ---------------- per-node alpha + sigmoid ----------------
__global__ __launch_bounds__(256)
void alpha_k(const float* __restrict__ xh, const float* __restrict__ attq,
             float* __restrict__ sa, int n, int C, int HC) {
    const int t = blockIdx.x * blockDim.x + threadIdx.x;
    if (t >= n * HEADS) return;
    const int nd = t >> 2, h = t & 3;
    const float* xr = &xh[(size_t)nd * HC + h * C];
    const float* q = &attq[h * C];
    float s = 0.f;
    for (int c = 0; c < C; c += 4) {
        float4 a = *(const float4*)&xr[c];
        float4 b = *(const float4*)&q[c];
        s += a.x * b.x + a.y * b.y + a.z * b.z + a.w * b.w;
    }
    sa[t] = 1.0f / (1.0f + __expf(-s));
}

// ---------------- CSR build (dst-sorted), once per launch ----------------
__global__ __launch_bounds__(256)
void hist_k(const int* __restrict__ dst, int* __restrict__ deg, int E) {
    int e = blockIdx.x * 256 + threadIdx.x;
    if (e < E) atomicAdd(&deg[dst[e]], 1);
}

__global__ __launch_bounds__(256)
void scan1_k(const int* __restrict__ deg, int* __restrict__ ro,
             int* __restrict__ bsum, int n) {
    __shared__ int s[256];
    int i = blockIdx.x * 256 + threadIdx.x;
    int v = (i < n) ? deg[i] : 0;
    s[threadIdx.x] = v;
    __syncthreads();
    for (int off = 1; off < 256; off <<= 1) {
        int t = (threadIdx.x >= off) ? s[threadIdx.x - off] : 0;
        __syncthreads();
        s[threadIdx.x] += t;
        __syncthreads();
    }
    if (i < n) ro[i] = s[threadIdx.x] - v;
    if (threadIdx.x == 255) bsum[blockIdx.x] = s[255];
}

__global__ __launch_bounds__(256)
void scan2_k(int* __restrict__ bsum, int nb) {
    __shared__ int s[256];
    int v = (threadIdx.x < nb) ? bsum[threadIdx.x] : 0;
    s[threadIdx.x] = v;
    __syncthreads();
    for (int off = 1; off < 256; off <<= 1) {
        int t = (threadIdx.x >= off) ? s[threadIdx.x - off] : 0;
        __syncthreads();
        s[threadIdx.x] += t;
        __syncthreads();
    }
    if (threadIdx.x < nb) bsum[threadIdx.x] = s[threadIdx.x] - v;
}

__global__ __launch_bounds__(256)
void scan3_k(int* __restrict__ ro, int* __restrict__ cur,
             const int* __restrict__ bsum, int n, int E) {
    int i = blockIdx.x * 256 + threadIdx.x;
    if (i < n) {
        int r = ro[i] + bsum[i >> 8];
        ro[i] = r;
        cur[i] = r;
    }
    if (i == 0) ro[n] = E;
}

__global__ __launch_bounds__(256)
void scatter_idx_k(const int* __restrict__ src, const int* __restrict__ dst,
                   int* __restrict__ cur, int* __restrict__ csr_src, int E) {
    int e = blockIdx.x * 256 + threadIdx.x;
    if (e >= E) return;
    int d = dst[e];
    int pos = atomicAdd(&cur[d], 1);
    csr_src[pos] = src[e];
}

// ---------------- fused logit+softmax+aggregate+epilogue ----------------
// One wave per node (R5 skeleton). 32-edge chunks:
//   logit pass: 2 (edge,head) per lane (j and j+16), both sets of row loads
//   issued together (2x memory-level parallelism); xd quarter hoisted to
//   registers (was re-read per edge). w/si staged via per-wave LDS.
//   agg loop: 8 independent row gathers per iteration.
template <int C, bool CONCAT>
__global__ __launch_bounds__(256)
void fused_edge_k(const int* __restrict__ ro, const int* __restrict__ csr_src,
                  const float* __restrict__ xh, const float* __restrict__ sa,
                  const float* __restrict__ attv, const float* __restrict__ bias,
                  float* __restrict__ outp, int n) {
    constexpr int HC = 4 * C;
    constexpr int QH = C / 4;        // float4 chunks per head quarter
    constexpr bool DUAL = (C <= 32);
    const int wid = threadIdx.x >> 6;
    const int lane = threadIdx.x & 63;
    const int node = blockIdx.x * 4 + wid;

    __shared__ float wbuf[4][32 * 4];
    __shared__ int sibuf[4][32];
    __shared__ float avs[HC];
    for (int i = threadIdx.x; i < HC; i += 256) avs[i] = attv[i];
    __syncthreads();
    if (node >= n) return;

    const float4* __restrict__ xh4 = (const float4*)xh;
    const float4* __restrict__ avs4 = (const float4*)avs;
    const int s0 = ro[node], s1 = ro[node + 1];

    // logit mapping
    const int e_loc = lane >> 2;
    const int h_l = lane & 3;
    const float sad = sa[node * 4 + h_l];

    // hoisted dst-row quarter (registers, read once per node)
    float4 xd[QH];
    #pragma unroll
    for (int i = 0; i < QH; ++i)
        xd[i] = xh4[(size_t)node * C + h_l * QH + i];

    // aggregation mapping
    const int half = DUAL ? (lane >> 5) : 0;
    const int q = DUAL ? (lane & 31) : lane;
    const int h_a = (q < C) ? (q / QH) : 0;

    float4 acc = make_float4(0.f, 0.f, 0.f, 0.f);
    float ssum = 0.f;

    for (int base = s0; base < s1; base += 32) {
        const int cnt = min(32, s1 - base);
        // ---- logit pass: 32 edges, 2 per lane ----
        {
            const int j0 = base + e_loc;
            const int j1 = j0 + 16;
            const bool v0 = (j0 < s1), v1 = (j1 < s1);
            const int si0 = v0 ? csr_src[j0] : node;
            const int si1 = v1 ? csr_src[j1] : node;
            const float sas0 = sa[si0 * 4 + h_l];
            const float sas1 = sa[si1 * 4 + h_l];
            float4 xs0[QH], xs1[QH];
            #pragma unroll
            for (int i = 0; i < QH; ++i)
                xs0[i] = xh4[(size_t)si0 * C + h_l * QH + i];
            #pragma unroll
            for (int i = 0; i < QH; ++i)
                xs1[i] = xh4[(size_t)si1 * C + h_l * QH + i];
            float wb0 = 0.f, wb1 = 0.f;
            #pragma unroll
            for (int i = 0; i < QH; ++i) {
                const float4 b = xd[i];
                const float4 v = avs4[h_l * QH + i];
                const float4 a0 = xs0[i];
                const float4 a1 = xs1[i];
                float t;
                t = a0.x + b.x; t = t > 0.f ? t : 0.01f * t; wb0 += v.x * t;
                t = a0.y + b.y; t = t > 0.f ? t : 0.01f * t; wb0 += v.y * t;
                t = a0.z + b.z; t = t > 0.f ? t : 0.01f * t; wb0 += v.z * t;
                t = a0.w + b.w; t = t > 0.f ? t : 0.01f * t; wb0 += v.w * t;
                t = a1.x + b.x; t = t > 0.f ? t : 0.01f * t; wb1 += v.x * t;
                t = a1.y + b.y; t = t > 0.f ? t : 0.01f * t; wb1 += v.y * t;
                t = a1.z + b.z; t = t > 0.f ? t : 0.01f * t; wb1 += v.z * t;
                t = a1.w + b.w; t = t > 0.f ? t : 0.01f * t; wb1 += v.w * t;
            }
            const float wa0 = 1.0f - fabsf(sad - sas0);
            const float wa1 = 1.0f - fabsf(sad - sas1);
            const float w0 = v0 ? __expf(fminf(wa0 * wb0, 60.f)) : 0.f;
            const float w1 = v1 ? __expf(fminf(wa1 * wb1, 60.f)) : 0.f;
            ssum += w0 + w1;
            wbuf[wid][e_loc * 4 + h_l] = w0;
            wbuf[wid][(e_loc + 16) * 4 + h_l] = w1;
            if (h_l == 0) {
                sibuf[wid][e_loc] = si0;
                sibuf[wid][e_loc + 16] = si1;
            }
        }
        // ---- aggregation: padded slots carry w=0, no guards ----
        const int padded = ((cnt + 15) >> 4) << 4;
        if (q < C) {
            if (DUAL) {
                for (int i = 0; i < padded; i += 16) {
                    #pragma unroll
                    for (int k = 0; k < 8; ++k) {
                        const int e = i + half + 2 * k;
                        const int sie = sibuf[wid][e];
                        const float we = wbuf[wid][e * 4 + h_a];
                        const float4 v = xh4[(size_t)sie * C + q];
                        acc.x += we * v.x;
                        acc.y += we * v.y;
                        acc.z += we * v.z;
                        acc.w += we * v.w;
                    }
                }
            } else {
                for (int i = 0; i < padded; i += 8) {
                    #pragma unroll
                    for (int k = 0; k < 8; ++k) {
                        const int e = i + k;
                        const int sie = sibuf[wid][e];
                        const float we = wbuf[wid][e * 4 + h_a];
                        const float4 v = xh4[(size_t)sie * C + q];
                        acc.x += we * v.x;
                        acc.y += we * v.y;
                        acc.z += we * v.z;
                        acc.w += we * v.w;
                    }
                }
            }
        }
    }

    // combine dual halves
    if (DUAL) {
        acc.x += __shfl_xor(acc.x, 32, 64);
        acc.y += __shfl_xor(acc.y, 32, 64);
        acc.z += __shfl_xor(acc.z, 32, 64);
        acc.w += __shfl_xor(acc.w, 32, 64);
    }

    // per-head sum of weights: reduce across lanes sharing (lane & 3)
    #pragma unroll
    for (int off = 4; off < 64; off <<= 1) ssum += __shfl_xor(ssum, off, 64);
    const float stot = __shfl(ssum, h_a, 64);
    const float inv = 1.0f / (stot + 1e-20f);
    acc.x *= inv; acc.y *= inv; acc.z *= inv; acc.w *= inv;

    if (CONCAT) {
        if (q < C && half == 0) {
            const float4 b = ((const float4*)bias)[q];
            float4 v = make_float4(acc.x + b.x, acc.y + b.y, acc.z + b.z, acc.w + b.w);
            v.x = v.x > 0.f ? v.x : __expf(v.x) - 1.0f;
            v.y = v.y > 0.f ? v.y : __expf(v.y) - 1.0f;
            v.z = v.z > 0.f ? v.z : __expf(v.z) - 1.0f;
            v.w = v.w > 0.f ? v.w : __expf(v.w) - 1.0f;
            *(float4*)&outp[(size_t)node * HC + q * 4] = v;
        }
    } else {
        // head-mean via shuffles: lanes q<QH gather the other 3 heads' chunks
        const int qq = (q < QH) ? q : 0;
        const float x1 = __shfl(acc.x, qq + QH, 64);
        const float y1 = __shfl(acc.y, qq + QH, 64);
        const float z1 = __shfl(acc.z, qq + QH, 64);
        const float w1 = __shfl(acc.w, qq + QH, 64);
        const float x2 = __shfl(acc.x, qq + 2 * QH, 64);
        const float y2 = __shfl(acc.y, qq + 2 * QH, 64);
        const float z2 = __shfl(acc.z, qq + 2 * QH, 64);
        const float w2 = __shfl(acc.w, qq + 2 * QH, 64);
        const float x3 = __shfl(acc.x, qq + 3 * QH, 64);
        const float y3 = __shfl(acc.y, qq + 3 * QH, 64);
        const float z3 = __shfl(acc.z, qq + 3 * QH, 64);
        const float w3 = __shfl(acc.w, qq + 3 * QH, 64);
        if (q < QH && half == 0) {
            const float4 b = ((const float4*)bias)[q];
            float4 v;
            v.x = 0.25f * (acc.x + x1 + x2 + x3) + b.x;
            v.y = 0.25f * (acc.y + y1 + y2 + y3) + b.y;
            v.z = 0.25f * (acc.z + z1 + z2 + z3) + b.z;
            v.w = 0.25f * (acc.w + w1 + w2 + w3) + b.w;
            *(float4*)&outp[(size_t)node * C + q * 4] = v;
        }
    }
}

extern "C" void kernel_launch(void* const* d_in, const int* in_sizes, int n_in,
                              void* d_out, int out_size, void* d_ws, size_t ws_size,
                              hipStream_t stream) {
    const float* x      = (const float*)d_in[0];
    const int*   src    = (const int*)d_in[1];
    const int*   dst    = (const int*)d_in[2];
    const float* lin1   = (const float*)d_in[3];
    const float* att_q1 = (const float*)d_in[4];
    const float* att_v1 = (const float*)d_in[5];
    const float* bias1  = (const float*)d_in[6];
    const float* lin2   = (const float*)d_in[7];
    const float* att_q2 = (const float*)d_in[8];
    const float* att_v2 = (const float*)d_in[9];
    const float* bias2  = (const float*)d_in[10];
    float* outp = (float*)d_out;

    const int n = in_sizes[0] / 256;
    const int E = in_sizes[1];
    const int nh = n * HEADS;
    const int NB = (n + 255) / 256;

    char* wsb = (char*)d_ws;
    size_t o = 0;
    float* xh     = (float*)(wsb + o); o += (size_t)n * 160 * 4;
    float* accb   = (float*)(wsb + o); o += (size_t)n * 160 * 4;
    float* sa     = (float*)(wsb + o); o += (size_t)nh * 4;
    int* csr_src  = (int*)(wsb + o); o += (size_t)E * 4;
    int* deg      = (int*)(wsb + o); o += (size_t)n * 4;
    int* ro       = (int*)(wsb + o); o += (size_t)(n + 1) * 4;
    int* cur      = (int*)(wsb + o); o += (size_t)n * 4;
    int* bsum     = (int*)(wsb + o); o += 256 * 4;

    dim3 blk(256);
    const int EG = (E + 255) / 256;

    // ---- CSR build (dst is layer-invariant: build once, use twice) ----
    hipMemsetAsync(deg, 0, (size_t)n * 4, stream);
    hist_k<<<EG, blk, 0, stream>>>(dst, deg, E);
    scan1_k<<<NB, blk, 0, stream>>>(deg, ro, bsum, n);
    scan2_k<<<1, blk, 0, stream>>>(bsum, NB);
    scan3_k<<<NB, blk, 0, stream>>>(ro, cur, bsum, n, E);
    scatter_idx_k<<<EG, blk, 0, stream>>>(src, dst, cur, csr_src, E);

    // ================= layer 1: C=32, HC=128, K=256 =================
    gemm_k<<<dim3((n + 127) / 128, 128 / 32), blk, 0, stream>>>(x, lin1, xh, n, 256, 128);
    alpha_k<<<(nh + 255) / 256, blk, 0, stream>>>(xh, att_q1, sa, n, 32, 128);
    fused_edge_k<32, true><<<(n + 3) / 4, blk, 0, stream>>>(ro, csr_src, xh, sa, att_v1, bias1, accb, n);

    // ================= layer 2: C=40, HC=160, K=128 =================
    gemm_k<<<dim3((n + 127) / 128, 160 / 32), blk, 0, stream>>>(accb, lin2, xh, n, 128, 160);
    alpha_k<<<(nh + 255) / 256, blk, 0, stream>>>(xh, att_q2, sa, n, 40, 160);
    fused_edge_k<40, false><<<(n + 3) / 4, blk, 0, stream>>>(ro, csr_src, xh, sa, att_v2, bias2, outp, n);
}